// Round 6
// baseline (2613.476 us; speedup 1.0000x reference)
//
#include <hip/hip_runtime.h>
#include <hip/hip_bf16.h>
#include <math.h>

#define B_ 256
#define L_ 512
#define V_ 256
#define E_ 256
#define H_ 1024
#define NSTEP_ 513   // flag-step stride (H_1 .. H_512)

typedef float  f32x4  __attribute__((ext_vector_type(4)));
typedef short  bf16x8 __attribute__((ext_vector_type(8)));

static __device__ __forceinline__ ushort f2bf(float v) {
    __hip_bfloat16 b = __float2bfloat16(v);
    return *reinterpret_cast<ushort*>(&b);
}

// fast tanh: 1 - 2/(exp(2z)+1); exact limits at +/-inf, ~1e-7 rel err
static __device__ __forceinline__ float ftanh(float z) {
    float e = __expf(2.f * z);
    return 1.f - 2.f / (e + 1.f);
}

// ---------- prep: transpose f32 [R][C] -> bf16 [C][R] ----------
__global__ void k_transpose_bf16(const float* __restrict__ in, ushort* __restrict__ out,
                                 int R, int C) {
    __shared__ float tile[64][65];
    int bx = blockIdx.x;           // over C/64
    int by = blockIdx.y;           // over R/64
    int tid = threadIdx.x;
    int g = tid >> 6, l = tid & 63;
    for (int i = 0; i < 16; ++i) {
        int r = g * 16 + i;
        tile[r][l] = in[(size_t)(by * 64 + r) * C + bx * 64 + l];
    }
    __syncthreads();
    for (int i = 0; i < 16; ++i) {
        int c = g * 16 + i;
        out[(size_t)(bx * 64 + c) * R + by * 64 + l] = f2bf(tile[l][c]);
    }
}

// ---------- prep: f32 -> bf16 copy ----------
__global__ void k_f32_to_bf16(const float* __restrict__ in, ushort* __restrict__ out, int n) {
    int i = blockIdx.x * blockDim.x + threadIdx.x;
    if (i < n) out[i] = f2bf(in[i]);
}

// ---------- prep: zero the flag array ----------
__global__ void k_zero(unsigned* __restrict__ p, int n) {
    int i = blockIdx.x * blockDim.x + threadIdx.x;
    if (i < n) p[i] = 0u;
}

// ---------- prep: proj[t][h] = sum_e emb[t][e] * W_e[e][h]  (f32) ----------
__global__ void k_proj(const float* __restrict__ emb, const float* __restrict__ We,
                       float* __restrict__ proj) {
    __shared__ float er[E_];
    int t = blockIdx.x;
    int h = blockIdx.y * 256 + threadIdx.x;
    er[threadIdx.x] = emb[t * E_ + threadIdx.x];   // blockDim.x == 256 == E_
    __syncthreads();
    float acc = 0.f;
#pragma unroll 8
    for (int e = 0; e < E_; ++e) acc += er[e] * We[(size_t)e * H_ + h];
    proj[(size_t)t * H_ + h] = acc;
}

// ---------- persistent scan kernel ----------
// 256 blocks, 1/CU (LDS 136KB). Block (rg=bid&7, cg=bid>>3) owns h rows
// [rg*32,+32) x cols [cg*32,+32). blockIdx-only assignment (no placement
// assumptions). Exchange at the L3 coherence point (sc0 sc1, R3/R5-proven).
// W_h^T quadrant slice lives in 128 VGPRs per lane (no LDS reads for B).
// lds_h parity double-buffer: B-phase (logits, old buffer) overlaps the
// in-flight stage loads of the new step's h panel.
__global__ __launch_bounds__(256, 1) void k_scan(
    const int* __restrict__ x, const float* __restrict__ proj,
    const ushort* __restrict__ WhT, const ushort* __restrict__ WoT,
    ushort* __restrict__ ring, float* __restrict__ logits,
    float* __restrict__ final_h, unsigned* __restrict__ flags)
{
    __shared__ ushort lds_h[2][32 * 1024];  // H_s panels, swizzled, parity ping-pong (128KB)
    __shared__ float  red[256 * 5];         // B-phase reduce, stride-5 (5KB)
    __shared__ ushort stile[32 * 40];       // A-phase store repack, stride-40 (2.5KB)

    int tid = threadIdx.x;
    int w = tid >> 6, lane = tid & 63;
    int l15 = lane & 15, l4 = lane >> 4;
    int bid = blockIdx.x;
    int rg = bid & 7;             // row-group
    int cg = bid >> 3;            // 0..31 col-group
    int r0 = rg * 32, c0 = cg * 32;

    // A-phase wave quadrant: rows a*16.., cols bc*16..
    int a = w >> 1, bc = w & 1;
    int arow = a * 16 + l15;
    int as = (arow & 7) << 4;
    int gcol = c0 + bc * 16 + l15;

    // --- W_h^T quadrant fragments into registers (one-time, plain loads)
    bf16x8 wreg[32];
    {
        const ushort* wp = WhT + (size_t)(c0 + bc * 16 + l15) * H_ + l4 * 8;
#pragma unroll
        for (int kk = 0; kk < 32; ++kk)
            wreg[kk] = *(const bf16x8*)(wp + kk * 32);
    }

    // B-phase constants: logits rows r0+(cg&1)*16..+16, vocab cols (cg>>1)*16..+16
    int lrg = cg & 1, vcol0 = (cg >> 1) * 16;
    int srow = lrg * 16 + l15;
    int sroff = srow * 2048;
    int hs2 = (srow & 7) << 4;
    const ushort* wo = WoT + (size_t)(vcol0 + l15) * H_;
    int bbase = (w == 1) ? 0 : (w == 2) ? 11 : 22;   // K chunks for waves 1..3
    int bcnt  = (w == 3) ? 10 : 11;

    for (int s = 0; s <= NSTEP_; ++s) {
        // --- prefetch x/proj gathers for A(s) (read-only, L2-warm)
        float pv[4];
        if (s < L_) {
#pragma unroll
            for (int j = 0; j < 4; ++j) {
                int grow = r0 + a * 16 + l4 * 4 + j;
                pv[j] = proj[(size_t)x[grow * L_ + s] * H_ + gcol];
            }
        }

        // --- wave0: poll the 32 per-producer flags for H_s
        if (w == 0 && s >= 1 && s <= L_) {
            const unsigned* fp = flags + ((size_t)rg * NSTEP_ + s) * 32 + lane;
            unsigned v = 1u;
            while (true) {
                if (lane < 32) {
                    asm volatile("global_load_dword %0, %1, off sc0 sc1\n\t"
                                 "s_waitcnt vmcnt(0)"
                                 : "=v"(v) : "v"(fp) : "memory");
                }
                if (__ballot(v != 0u) == ~0ull) break;
            }
        }
        __syncthreads();   // flags seen -> ring slot s&1 is valid for everyone

        // --- issue stage loads for H_s (fly during B-phase below)
        f32x4 tv[16];
        if (s <= L_) {
            const char* hsrc = (const char*)(ring + (size_t)(s & 1) * B_ * H_
                                             + (size_t)r0 * H_) + tid * 16;
#pragma unroll
            for (int i = 0; i < 16; ++i) {
                asm volatile("global_load_dwordx4 %0, %1, off sc0 sc1"
                             : "=v"(tv[i]) : "v"(hsrc + i * 4096) : "memory");
            }
        }

        // --- B phase (waves 1-3): logits col s-2 from the OLD buffer H_{s-1}
        if (w >= 1 && s >= 2) {
            const char* hbp = (const char*)lds_h[(s & 1) ^ 1] + sroff;
            f32x4 lacc = {0.f, 0.f, 0.f, 0.f};
            for (int kk = 0; kk < bcnt; ++kk) {
                int k = (bbase + kk) * 32 + l4 * 8;
                bf16x8 af = *(const bf16x8*)(hbp + ((2 * k) ^ hs2));
                bf16x8 bf = *(const bf16x8*)(wo + k);
                lacc = __builtin_amdgcn_mfma_f32_16x16x32_bf16(af, bf, lacc, 0, 0, 0);
            }
#pragma unroll
            for (int j = 0; j < 4; ++j) red[tid * 5 + j] = lacc[j];
        }

        // --- complete the stage: drain loads, swizzled ds_write into buf[s&1]
        if (s <= L_) {
            asm volatile("s_waitcnt vmcnt(0)" ::: "memory");
            char* hd = (char*)lds_h[s & 1];
#pragma unroll
            for (int i = 0; i < 16; ++i) {
                int o = i * 4096 + tid * 16;
                int row = o >> 11, b = o & 2047;
                *(f32x4*)(hd + row * 2048 + (b ^ ((row & 7) << 4))) = tv[i];
            }
        }
        __syncthreads();   // lds_h[s&1] = H_s; red[] complete

        // --- wave0: store logits col s-2 (fire-and-forget, write-back L2)
        if (w == 0 && s >= 2) {
            int growb = r0 + lrg * 16 + l4 * 4;
#pragma unroll
            for (int j = 0; j < 4; ++j) {
                float ssum = red[(64 + lane) * 5 + j] + red[(128 + lane) * 5 + j]
                           + red[(192 + lane) * 5 + j];
                logits[((size_t)(growb + j) * L_ + (s - 2)) * V_ + vcol0 + l15] = ssum;
            }
        }

        // --- A phase: H_{s+1} tile = tanh(pv + H_s @ W_h); B-frags from regs
        if (s < L_) {
            const char* ha = (const char*)lds_h[s & 1] + arow * 2048;
            f32x4 acc0 = {0.f, 0.f, 0.f, 0.f};
            f32x4 acc1 = {0.f, 0.f, 0.f, 0.f};
#pragma unroll
            for (int kk = 0; kk < 32; kk += 2) {
                int kb0 = (kk * 32 + l4 * 8) * 2;
                int kb1 = ((kk + 1) * 32 + l4 * 8) * 2;
                bf16x8 af0 = *(const bf16x8*)(ha + (kb0 ^ as));
                bf16x8 af1 = *(const bf16x8*)(ha + (kb1 ^ as));
                acc0 = __builtin_amdgcn_mfma_f32_16x16x32_bf16(af0, wreg[kk],     acc0, 0, 0, 0);
                acc1 = __builtin_amdgcn_mfma_f32_16x16x32_bf16(af1, wreg[kk + 1], acc1, 0, 0, 0);
            }
#pragma unroll
            for (int j = 0; j < 4; ++j) {
                int lrow = a * 16 + l4 * 4 + j;
                float hv = ftanh((acc0[j] + acc1[j]) + pv[j]);
                stile[lrow * 40 + bc * 16 + l15] = f2bf(hv);
                if (s == L_ - 1) final_h[(size_t)(r0 + lrow) * H_ + gcol] = hv;
            }
            __syncthreads();       // stile complete
            if (tid < 128) {
                int row = tid >> 2, seg = tid & 3;
                f32x4 d = *(const f32x4*)&stile[row * 40 + seg * 8];
                char* dst = (char*)(ring + (size_t)((s + 1) & 1) * B_ * H_
                                    + (size_t)(r0 + row) * H_ + c0 + seg * 8);
                asm volatile("global_store_dwordx4 %0, %1, off sc0 sc1"
                             :: "v"(dst), "v"(d) : "memory");
            }
            asm volatile("s_waitcnt vmcnt(0)" ::: "memory");   // data at coherence point
            __syncthreads();                                   // ALL producers drained
            if (tid == 0) {
                unsigned* fdst = flags + ((size_t)rg * NSTEP_ + (s + 1)) * 32 + cg;
                unsigned one = 1u;
                asm volatile("global_store_dword %0, %1, off sc0 sc1"
                             :: "v"(fdst), "v"(one) : "memory");
            }
        }
    }
}

extern "C" void kernel_launch(void* const* d_in, const int* in_sizes, int n_in,
                              void* d_out, int out_size, void* d_ws, size_t ws_size,
                              hipStream_t stream)
{
    const int*   x   = (const int*)d_in[0];
    const float* hid = (const float*)d_in[1];
    const float* emb = (const float*)d_in[2];
    const float* We  = (const float*)d_in[3];
    const float* Wh  = (const float*)d_in[4];
    const float* Wo  = (const float*)d_in[5];

    float* logits  = (float*)d_out;                       // [B][L][V] f32
    float* final_h = logits + (size_t)B_ * L_ * V_;       // [B][H] f32

    char* ws = (char*)d_ws;
    float*    proj  = (float*)(ws);                                   // 1 MB   f32 [V][H]
    ushort*   WhT   = (ushort*)(ws + (1u << 20));                     // 2 MB   bf16 [H][H]^T
    ushort*   WoT   = (ushort*)(ws + 3u * (1u << 20));                // 0.5 MB bf16 [V][H]^T
    ushort*   ring  = (ushort*)(ws + 3u * (1u << 20) + (1u << 19));   // 1 MB   bf16 2x[B][H]
    unsigned* flags = (unsigned*)(ws + 4u * (1u << 20) + (1u << 19)); // 513 KB u32 [8][513][32]

    // prep (stream-ordered before the persistent kernel)
    k_zero<<<dim3(NSTEP_), 256, 0, stream>>>(flags, 8 * NSTEP_ * 32);
    k_transpose_bf16<<<dim3(16, 16), 256, 0, stream>>>(Wh, WhT, H_, H_);
    k_transpose_bf16<<<dim3(4, 16),  256, 0, stream>>>(Wo, WoT, H_, V_);
    k_f32_to_bf16<<<dim3(1024), 256, 0, stream>>>(hid, ring, B_ * H_);   // H_0 -> slot 0
    k_proj<<<dim3(256, 4), 256, 0, stream>>>(emb, We, proj);

    // one persistent kernel does all 512 steps + fused logits
    k_scan<<<dim3(256), 256, 0, stream>>>(x, proj, WhT, WoT, ring,
                                          logits, final_h, flags);
}